// Round 1
// baseline (97.424 us; speedup 1.0000x reference)
//
#include <hip/hip_runtime.h>
#include <hip/hip_bf16.h>

// Problem dims (fixed by the reference): B=64, T=2048, D=256
#define BB  64
#define TT  2048
#define DD  256
#define EPSV 1e-7f

typedef __attribute__((ext_vector_type(8))) short bf16x8;   // MFMA A/B fragment (4 VGPR)
typedef __attribute__((ext_vector_type(4))) float f32x4;    // MFMA C/D fragment

__device__ __forceinline__ ushort f2bf(float f) {
    union { float f; unsigned u; } v; v.f = f;
    unsigned u = v.u;
    // round-to-nearest-even
    unsigned r = (u + 0x7FFFu + ((u >> 16) & 1u)) >> 16;
    return (ushort)r;
}

__device__ __forceinline__ float bf2f(ushort h) {
    union { unsigned u; float f; } v; v.u = ((unsigned)h) << 16;
    return v.f;
}

__device__ __forceinline__ float tanh_fast(float x) {
    // tanh(x) = 1 - 2/(exp(2x)+1); exp overflow/underflow saturate correctly to +-1
    float e = __expf(2.0f * x);
    return 1.0f - 2.0f * __builtin_amdgcn_rcpf(e + 1.0f);
}

// ---------------------------------------------------------------------------
// prep: blocks 0..63  -> bias[b][e] = sum_d aspect[b,d]*aspect_w[d,e] + sentence[b,d]*sent_w[d,e]
//       blocks 64..95 -> W_frag: context_w (f32 [256][256]) -> bf16 in MFMA B-fragment order
//       W_frag element index: ((kk*16+n)*64 + lane)*8 + j  <->  W[kk*32+(lane>>4)*8+j][n*16+(lane&15)]
// ---------------------------------------------------------------------------
__global__ __launch_bounds__(256) void prep_kernel(
    const float* __restrict__ aspect, const float* __restrict__ sentence,
    const float* __restrict__ context_w, const float* __restrict__ aspect_w,
    const float* __restrict__ sent_w,
    float* __restrict__ bias_ws, ushort* __restrict__ wfrag_ws)
{
    const int blk = blockIdx.x, tid = threadIdx.x;
    if (blk < 64) {
        const int b = blk, e = tid;
        float s = 0.f;
        for (int d = 0; d < DD; ++d) {
            s = fmaf(aspect[b * DD + d],   aspect_w[d * DD + e], s);
            s = fmaf(sentence[b * DD + d], sent_w[d * DD + e],   s);
        }
        bias_ws[b * DD + e] = s;
    } else {
        const int flat = (blk - 64) * 256 + tid;     // 0..8191
        const int lane = flat & 63;
        const int kn   = flat >> 6;                  // 0..127  (= kk*16 + n)
        const int kk   = kn >> 4;
        const int n    = kn & 15;
        const int krow = kk * 32 + ((lane >> 4) << 3);
        const int col  = n * 16 + (lane & 15);
        bf16x8 v;
        #pragma unroll
        for (int j = 0; j < 8; ++j)
            v[j] = (short)f2bf(context_w[(size_t)(krow + j) * DD + col]);
        *reinterpret_cast<bf16x8*>(wfrag_ws + (size_t)flat * 8) = v;
    }
}

// ---------------------------------------------------------------------------
// main: one block = one (b, 64-row t-tile). 4 waves x 16 rows each.
//  1) stage ctx tile fp32 -> bf16 in XOR-swizzled LDS
//  2) MFMA GEMM v[t,e] = ctx @ W  (K=256), epilogue tanh(v+bias)·aw -> g[t]
//  3) e[t] = exp(g)*mask ; fused unnormalized weighted sum over the 64 rows
// ---------------------------------------------------------------------------
__global__ __launch_bounds__(256) void attn_main(
    const float* __restrict__ ctx, const int* __restrict__ mask,
    const float* __restrict__ attend_w,
    const float* __restrict__ bias_ws, const ushort* __restrict__ wfrag_ws,
    float* __restrict__ partial_ws, float* __restrict__ esum_ws)
{
    __shared__ ushort ctx_lds[64 * 256];   // 32 KiB, XOR-swizzled rows (512 B row pitch)
    __shared__ float  bias_lds[256];
    __shared__ float  aw_lds[256];
    __shared__ float  evals[64];

    const int tid  = threadIdx.x;
    const int wave = tid >> 6;
    const int lane = tid & 63;
    const int tb   = blockIdx.x & 31;
    const int b    = blockIdx.x >> 5;
    const int t0   = tb * 64;

    bias_lds[tid] = bias_ws[b * DD + tid];
    aw_lds[tid]   = attend_w[tid];

    // ---- stage ctx tile: 64 rows x 256 f32 = 4096 float4, 16 per thread ----
    const float4* src = reinterpret_cast<const float4*>(ctx + (size_t)(b * TT + t0) * DD);
    #pragma unroll
    for (int i = 0; i < 16; ++i) {
        const int flat = i * 256 + tid;        // float4 index in tile
        const int row  = flat >> 6;            // 64 float4 per row
        const int c4   = flat & 63;
        const float4 v = src[flat];
        ushort4 h;
        h.x = f2bf(v.x); h.y = f2bf(v.y); h.z = f2bf(v.z); h.w = f2bf(v.w);
        const int kb = c4 * 8;                               // byte offset of 4 bf16
        const int sw = kb ^ ((row & 7) << 4);                // XOR swizzle (bits 4..6)
        *reinterpret_cast<ushort4*>(reinterpret_cast<char*>(ctx_lds) + row * 512 + sw) = h;
    }
    __syncthreads();

    // ---- GEMM: wave handles rows r0..r0+15, all 256 output cols ----
    const int r0   = wave * 16;
    const int arow = r0 + (lane & 15);
    const char* abase = reinterpret_cast<const char*>(ctx_lds) + arow * 512;
    const int asw = (arow & 7) << 4;
    const bf16x8* wf = reinterpret_cast<const bf16x8*>(wfrag_ws);

    f32x4 acc[16];
    #pragma unroll
    for (int n = 0; n < 16; ++n) acc[n] = (f32x4){0.f, 0.f, 0.f, 0.f};

    #pragma unroll
    for (int kk = 0; kk < 8; ++kk) {
        const int kb = kk * 64 + ((lane >> 4) << 4);         // byte offset of 8 bf16 along K
        const bf16x8 a = *reinterpret_cast<const bf16x8*>(abase + (kb ^ asw));
        #pragma unroll
        for (int n = 0; n < 16; ++n) {
            const bf16x8 bf = wf[(kk * 16 + n) * 64 + lane];
            acc[n] = __builtin_amdgcn_mfma_f32_16x16x32_bf16(a, bf, acc[n], 0, 0, 0);
        }
    }

    // ---- epilogue: g[row] = sum_e tanh(v+bias)*aw ----
    // C/D layout: col = n*16 + (lane&15), row = (lane>>4)*4 + j
    float gp0 = 0.f, gp1 = 0.f, gp2 = 0.f, gp3 = 0.f;
    #pragma unroll
    for (int n = 0; n < 16; ++n) {
        const int col = n * 16 + (lane & 15);
        const float bs = bias_lds[col];
        const float aw = aw_lds[col];
        gp0 = fmaf(tanh_fast(acc[n][0] + bs), aw, gp0);
        gp1 = fmaf(tanh_fast(acc[n][1] + bs), aw, gp1);
        gp2 = fmaf(tanh_fast(acc[n][2] + bs), aw, gp2);
        gp3 = fmaf(tanh_fast(acc[n][3] + bs), aw, gp3);
    }
    #pragma unroll
    for (int off = 1; off < 16; off <<= 1) {
        gp0 += __shfl_xor(gp0, off);
        gp1 += __shfl_xor(gp1, off);
        gp2 += __shfl_xor(gp2, off);
        gp3 += __shfl_xor(gp3, off);
    }
    if ((lane & 15) == 0) {
        const int rbase = r0 + ((lane >> 4) << 2);
        const int tg = b * TT + t0 + rbase;
        evals[rbase + 0] = __expf(gp0) * (float)mask[tg + 0];
        evals[rbase + 1] = __expf(gp1) * (float)mask[tg + 1];
        evals[rbase + 2] = __expf(gp2) * (float)mask[tg + 2];
        evals[rbase + 3] = __expf(gp3) * (float)mask[tg + 3];
    }
    __syncthreads();

    // ---- fused weighted sum: thread tid owns column d = tid ----
    float accd = 0.f, es = 0.f;
    #pragma unroll 8
    for (int r = 0; r < 64; ++r) {
        const float e = evals[r];
        const int byteoff = (tid * 2) ^ ((r & 7) << 4);
        const ushort hb = *reinterpret_cast<const ushort*>(
            reinterpret_cast<const char*>(ctx_lds) + r * 512 + byteoff);
        accd = fmaf(bf2f(hb), e, accd);
        es += e;
    }
    partial_ws[(size_t)(b * 32 + tb) * DD + tid] = accd;
    if (tid == 0) esum_ws[b * 32 + tb] = es;
}

// ---------------------------------------------------------------------------
// finalize: out[b,d] = (sum_tb partial) / (sum_tb esum + EPS) + sentence[b,d]
// ---------------------------------------------------------------------------
__global__ __launch_bounds__(256) void finalize_kernel(
    const float* __restrict__ sentence, const float* __restrict__ partial_ws,
    const float* __restrict__ esum_ws, float* __restrict__ out)
{
    const int b = blockIdx.x, d = threadIdx.x;
    float es = 0.f;
    #pragma unroll
    for (int tb = 0; tb < 32; ++tb) es += esum_ws[b * 32 + tb];
    float s = 0.f;
    #pragma unroll
    for (int tb = 0; tb < 32; ++tb) s += partial_ws[(size_t)(b * 32 + tb) * DD + d];
    out[b * DD + d] = s / (es + EPSV) + sentence[b * DD + d];
}

extern "C" void kernel_launch(void* const* d_in, const int* in_sizes, int n_in,
                              void* d_out, int out_size, void* d_ws, size_t ws_size,
                              hipStream_t stream)
{
    const float* ctx       = (const float*)d_in[0];
    const float* aspect    = (const float*)d_in[1];
    const float* sentence  = (const float*)d_in[2];
    const int*   mask      = (const int*)  d_in[3];
    // d_in[4] = context_w, d_in[5] = aspect_w, d_in[6] = sent_w, d_in[7] = attend_w
    const float* context_w = (const float*)d_in[4];
    const float* aspect_w  = (const float*)d_in[5];
    const float* sent_w    = (const float*)d_in[6];
    const float* attend_w  = (const float*)d_in[7];
    float* out = (float*)d_out;

    char* ws = (char*)d_ws;
    float*  bias_ws    = (float*) (ws);                      //  65536 B
    ushort* wfrag_ws   = (ushort*)(ws + 65536);              // 131072 B
    float*  esum_ws    = (float*) (ws + 65536 + 131072);     //   8192 B
    float*  partial_ws = (float*) (ws + 65536 + 131072 + 8192); // 2 MiB

    prep_kernel<<<96, 256, 0, stream>>>(aspect, sentence, context_w, aspect_w, sent_w,
                                        bias_ws, wfrag_ws);
    attn_main<<<BB * 32, 256, 0, stream>>>(ctx, mask, attend_w, bias_ws, wfrag_ws,
                                           partial_ws, esum_ws);
    finalize_kernel<<<BB, 256, 0, stream>>>(sentence, partial_ws, esum_ws, out);
}

// Round 2
// 58.898 us; speedup vs baseline: 1.6541x; 1.6541x over previous
//
#include <hip/hip_runtime.h>
#include <hip/hip_bf16.h>

// Problem dims (fixed by the reference): B=64, T=2048, D=256
#define BB  64
#define TT  2048
#define DD  256
#define EPSV 1e-7f
#define NTILE 4     // 64-row tiles per attn block
#define NBLK  512   // attn blocks (NBLK*NTILE*64 == BB*TT)

typedef __attribute__((ext_vector_type(8))) short bf16x8;   // MFMA A/B fragment (4 VGPR)
typedef __attribute__((ext_vector_type(4))) float f32x4;    // MFMA C/D fragment

__device__ __forceinline__ ushort f2bf(float f) {
    union { float f; unsigned u; } v; v.f = f;
    unsigned u = v.u;
    unsigned r = (u + 0x7FFFu + ((u >> 16) & 1u)) >> 16;   // RNE
    return (ushort)r;
}

__device__ __forceinline__ float bf2f(ushort h) {
    union { unsigned u; float f; } v; v.u = ((unsigned)h) << 16;
    return v.f;
}

__device__ __forceinline__ float tanh_fast(float x) {
    // tanh(x) = 1 - 2/(exp(2x)+1); saturates correctly at +-1
    float e = __expf(2.0f * x);
    return 1.0f - 2.0f * __builtin_amdgcn_rcpf(e + 1.0f);
}

// ---------------------------------------------------------------------------
// prep: blocks 0..255   -> bias partials: block b*4+q covers d in [q*64, q*64+64)
//       blocks 256..287 -> W_frag: context_w (f32 [256][256]) -> bf16 MFMA B-frag order
//       W_frag: flat = (kk*16+n)*64 + lane, elem j <-> W[kk*32+(lane>>4)*8+j][n*16+(lane&15)]
// ---------------------------------------------------------------------------
__global__ __launch_bounds__(256) void prep_kernel(
    const float* __restrict__ aspect, const float* __restrict__ sentence,
    const float* __restrict__ context_w, const float* __restrict__ aspect_w,
    const float* __restrict__ sent_w,
    float* __restrict__ bias_part, ushort* __restrict__ wfrag_ws)
{
    const int blk = blockIdx.x, tid = threadIdx.x;
    if (blk < 256) {
        const int b = blk >> 2, q = blk & 3, e = tid;
        float s = 0.f;
        #pragma unroll 4
        for (int dd = 0; dd < 64; ++dd) {
            const int d = q * 64 + dd;
            s = fmaf(aspect[b * DD + d],   aspect_w[d * DD + e], s);
            s = fmaf(sentence[b * DD + d], sent_w[d * DD + e],   s);
        }
        bias_part[blk * DD + e] = s;
    } else {
        const int flat = (blk - 256) * 256 + tid;    // 0..8191
        const int lane = flat & 63;
        const int kn   = flat >> 6;
        const int kk   = kn >> 4;
        const int n    = kn & 15;
        const int krow = kk * 32 + ((lane >> 4) << 3);
        const int col  = n * 16 + (lane & 15);
        bf16x8 v;
        #pragma unroll
        for (int j = 0; j < 8; ++j)
            v[j] = (short)f2bf(context_w[(size_t)(krow + j) * DD + col]);
        *reinterpret_cast<bf16x8*>(wfrag_ws + (size_t)flat * 8) = v;
    }
}

// ---------------------------------------------------------------------------
// attn_main: persistent block, 512 thr / 8 waves, NTILE 64-row tiles,
// double-buffered LDS, B-fragments register-resident (16 per wave = its 32 cols).
// ---------------------------------------------------------------------------
__global__ __launch_bounds__(512, 2) void attn_main(
    const float* __restrict__ ctx, const int* __restrict__ mask,
    const float* __restrict__ attend_w,
    const float* __restrict__ bias_part, const ushort* __restrict__ wfrag_ws,
    float* __restrict__ partial_ws, float* __restrict__ esum_ws)
{
    __shared__ ushort ctx_lds[2][64 * 256];   // 2 x 32 KiB, XOR-swizzled rows (512 B pitch)
    __shared__ float  bias_lds[256];
    __shared__ float  aw_lds[256];
    __shared__ float  mask_lds[256];          // this block's 256 rows of mask, as float
    __shared__ float  gpart[8][64];           // per-wave partial g
    __shared__ float  evals[64];
    __shared__ float  part_d[8][256];         // weighted-sum partials per row-group

    const int tid  = threadIdx.x;
    const int wave = tid >> 6;
    const int lane = tid & 63;
    const int blk  = blockIdx.x;
    const int b    = blk >> 3;                // 8 blocks per batch element

    if (tid < 256) {
        bias_lds[tid] = bias_part[(b * 4 + 0) * DD + tid] + bias_part[(b * 4 + 1) * DD + tid]
                      + bias_part[(b * 4 + 2) * DD + tid] + bias_part[(b * 4 + 3) * DD + tid];
        aw_lds[tid]   = attend_w[tid];
        mask_lds[tid] = (float)mask[blk * 256 + tid];
    }

    // ---- preload this wave's 16 B-fragments (cols wave*32 .. +32) ----
    bf16x8 Bf[8][2];
    {
        const bf16x8* wf = reinterpret_cast<const bf16x8*>(wfrag_ws);
        #pragma unroll
        for (int kk = 0; kk < 8; ++kk) {
            Bf[kk][0] = wf[(kk * 16 + wave * 2 + 0) * 64 + lane];
            Bf[kk][1] = wf[(kk * 16 + wave * 2 + 1) * 64 + lane];
        }
    }

    const float4* src = reinterpret_cast<const float4*>(ctx);

    // ---- prologue: stage tile 0 into buf 0 ----
    {
        const size_t base = (size_t)(blk * NTILE) * 4096;
        char* dst = reinterpret_cast<char*>(ctx_lds[0]);
        #pragma unroll
        for (int i = 0; i < 8; ++i) {
            const int flat = i * 512 + tid, row = flat >> 6, c4 = flat & 63;
            const float4 v = src[base + flat];
            ushort4 h4; h4.x = f2bf(v.x); h4.y = f2bf(v.y); h4.z = f2bf(v.z); h4.w = f2bf(v.w);
            *reinterpret_cast<ushort4*>(dst + row * 512 + ((c4 * 8) ^ ((row & 7) << 4))) = h4;
        }
    }
    __syncthreads();

    float accd[4] = {0.f, 0.f, 0.f, 0.f};
    float es_tot = 0.f;

    for (int it = 0; it < NTILE; ++it) {
        const int cur = it & 1;

        // ---- T14: issue next tile's global loads now; convert+write after compute ----
        float4 sreg[8];
        if (it + 1 < NTILE) {
            const size_t base = (size_t)(blk * NTILE + it + 1) * 4096;
            #pragma unroll
            for (int i = 0; i < 8; ++i) sreg[i] = src[base + i * 512 + tid];
        }

        // ---- GEMM: wave covers all 64 rows x its 32 cols ----
        f32x4 acc[4][2];
        #pragma unroll
        for (int rt = 0; rt < 4; ++rt) {
            acc[rt][0] = (f32x4){0.f, 0.f, 0.f, 0.f};
            acc[rt][1] = (f32x4){0.f, 0.f, 0.f, 0.f};
        }
        const char* lb = reinterpret_cast<const char*>(ctx_lds[cur]);
        #pragma unroll
        for (int rt = 0; rt < 4; ++rt) {
            const int row = rt * 16 + (lane & 15);
            const char* ab = lb + row * 512;
            const int asw = (row & 7) << 4;
            #pragma unroll
            for (int kk = 0; kk < 8; ++kk) {
                const bf16x8 a = *reinterpret_cast<const bf16x8*>(
                    ab + ((kk * 64 + ((lane >> 4) << 4)) ^ asw));
                acc[rt][0] = __builtin_amdgcn_mfma_f32_16x16x32_bf16(a, Bf[kk][0], acc[rt][0], 0, 0, 0);
                acc[rt][1] = __builtin_amdgcn_mfma_f32_16x16x32_bf16(a, Bf[kk][1], acc[rt][1], 0, 0, 0);
            }
        }

        // ---- epilogue: partial g over this wave's 32 cols ----
        const int c0 = wave * 32 + (lane & 15), c1 = c0 + 16;
        const float bs0 = bias_lds[c0], aw0 = aw_lds[c0];
        const float bs1 = bias_lds[c1], aw1 = aw_lds[c1];
        #pragma unroll
        for (int rt = 0; rt < 4; ++rt) {
            float gp[4];
            #pragma unroll
            for (int j = 0; j < 4; ++j)
                gp[j] = tanh_fast(acc[rt][0][j] + bs0) * aw0
                      + tanh_fast(acc[rt][1][j] + bs1) * aw1;
            #pragma unroll
            for (int off = 1; off < 16; off <<= 1) {
                #pragma unroll
                for (int j = 0; j < 4; ++j) gp[j] += __shfl_xor(gp[j], off);
            }
            if ((lane & 15) == 0) {
                const int r = rt * 16 + ((lane >> 4) << 2);
                gpart[wave][r + 0] = gp[0]; gpart[wave][r + 1] = gp[1];
                gpart[wave][r + 2] = gp[2]; gpart[wave][r + 3] = gp[3];
            }
        }
        __syncthreads();

        // ---- evals + running esum (wave 0 only) ----
        if (tid < 64) {
            float g = 0.f;
            #pragma unroll
            for (int w = 0; w < 8; ++w) g += gpart[w][tid];
            const float e = __expf(g) * mask_lds[it * 64 + tid];
            evals[tid] = e;
            float s = e;
            #pragma unroll
            for (int off = 1; off < 64; off <<= 1) s += __shfl_xor(s, off);
            if (tid == 0) es_tot += s;
        }
        __syncthreads();

        // ---- fused weighted sum: thread owns 4 d's, row-group tid>>6 ----
        {
            const int h = tid >> 6;
            const int dby = (tid & 63) << 3;   // byte offset of 4 bf16
            #pragma unroll
            for (int rr = 0; rr < 8; ++rr) {
                const int r = h * 8 + rr;
                const float e = evals[r];
                const ushort4 hv = *reinterpret_cast<const ushort4*>(
                    lb + r * 512 + (dby ^ ((r & 7) << 4)));
                accd[0] = fmaf(bf2f(hv.x), e, accd[0]);
                accd[1] = fmaf(bf2f(hv.y), e, accd[1]);
                accd[2] = fmaf(bf2f(hv.z), e, accd[2]);
                accd[3] = fmaf(bf2f(hv.w), e, accd[3]);
            }
        }

        // ---- write next tile into the other buffer ----
        if (it + 1 < NTILE) {
            char* dst = reinterpret_cast<char*>(ctx_lds[cur ^ 1]);
            #pragma unroll
            for (int i = 0; i < 8; ++i) {
                const int flat = i * 512 + tid, row = flat >> 6, c4 = flat & 63;
                ushort4 h4;
                h4.x = f2bf(sreg[i].x); h4.y = f2bf(sreg[i].y);
                h4.z = f2bf(sreg[i].z); h4.w = f2bf(sreg[i].w);
                *reinterpret_cast<ushort4*>(dst + row * 512 + ((c4 * 8) ^ ((row & 7) << 4))) = h4;
            }
        }
        __syncthreads();
    }

    // ---- block epilogue: combine row-group partials, write per-block outputs ----
    {
        const int h = tid >> 6, d0 = (tid & 63) << 2;
        part_d[h][d0 + 0] = accd[0]; part_d[h][d0 + 1] = accd[1];
        part_d[h][d0 + 2] = accd[2]; part_d[h][d0 + 3] = accd[3];
    }
    __syncthreads();
    if (tid < 256) {
        float s = 0.f;
        #pragma unroll
        for (int h = 0; h < 8; ++h) s += part_d[h][tid];
        partial_ws[blk * DD + tid] = s;
    }
    if (tid == 0) esum_ws[blk] = es_tot;
}

// ---------------------------------------------------------------------------
// finalize: out[b,d] = (sum_i partial) / (sum_i esum + EPS) + sentence[b,d]
// ---------------------------------------------------------------------------
__global__ __launch_bounds__(256) void finalize_kernel(
    const float* __restrict__ sentence, const float* __restrict__ partial_ws,
    const float* __restrict__ esum_ws, float* __restrict__ out)
{
    const int b = blockIdx.x, d = threadIdx.x;
    float es = 0.f, s = 0.f;
    #pragma unroll
    for (int i = 0; i < 8; ++i) {
        es += esum_ws[b * 8 + i];
        s  += partial_ws[(b * 8 + i) * DD + d];
    }
    out[b * DD + d] = s / (es + EPSV) + sentence[b * DD + d];
}

extern "C" void kernel_launch(void* const* d_in, const int* in_sizes, int n_in,
                              void* d_out, int out_size, void* d_ws, size_t ws_size,
                              hipStream_t stream)
{
    const float* ctx       = (const float*)d_in[0];
    const float* aspect    = (const float*)d_in[1];
    const float* sentence  = (const float*)d_in[2];
    const int*   mask      = (const int*)  d_in[3];
    const float* context_w = (const float*)d_in[4];
    const float* aspect_w  = (const float*)d_in[5];
    const float* sent_w    = (const float*)d_in[6];
    const float* attend_w  = (const float*)d_in[7];
    float* out = (float*)d_out;

    char* ws = (char*)d_ws;
    ushort* wfrag_ws   = (ushort*)(ws);                       // 131072 B
    float*  bias_part  = (float*) (ws + 131072);              // 262144 B
    float*  esum_ws    = (float*) (ws + 131072 + 262144);     //   2048 B
    float*  partial_ws = (float*) (ws + 131072 + 262144 + 2048); // 524288 B

    prep_kernel<<<288, 256, 0, stream>>>(aspect, sentence, context_w, aspect_w, sent_w,
                                         bias_part, wfrag_ws);
    attn_main<<<NBLK, 512, 0, stream>>>(ctx, mask, attend_w, bias_part, wfrag_ws,
                                        partial_ws, esum_ws);
    finalize_kernel<<<BB, 256, 0, stream>>>(sentence, partial_ws, esum_ws, out);
}